// Round 1
// baseline (1583.311 us; speedup 1.0000x reference)
//
#include <hip/hip_runtime.h>
#include <math.h>

// ---------------------------------------------------------------------------
// HGT on MI355X — round 0 baseline (fp32, CSR-based edge softmax, no atomics
// in the float path).
//
// Structure per call:
//   1. Build CSR (rowptr, esrc) per relation (3x), reused across both layers.
//   2. Precompute combined weights Wc_k = Wk @ a_rel * (p_rel/sqrt(D)),
//      Wc_v = Wv @ m_rel  (12 small 128x128 matrices).
//   3. h0 = relu(x @ W_in + b)  -> written to d_out columns [0:128).
//   4. Per layer: q GEMMs, per relation {kr,vr} GEMMs + fused online-softmax
//      attention (1 wave / dst node), then out-GEMM with gelu-on-load and
//      sigmoid-skip epilogue -> d_out columns [(l+1)*128 : (l+2)*128).
// ---------------------------------------------------------------------------

#define HID 128

__device__ __forceinline__ float gelu_f(float x) {
    return 0.5f * x * (1.0f + erff(x * 0.70710678118654752f));
}

// ---------------------------------------------------------------------------
// GEMM: C[M,128] = epi(A[M,128] @ W[128,128] + bias)
// ACT_IN: 0 = identity, 1 = gelu applied to A elements on load
// EPI:    0 = bias only, 1 = bias+relu, 2 = skip-mix: a*o + (1-a)*Hprev
// Tile: 64 rows x 128 cols per 256-thread block, K chunked by 32.
// ---------------------------------------------------------------------------
template <int ACT_IN, int EPI>
__global__ __launch_bounds__(256) void hgt_gemm128(
    const float* __restrict__ A, int lda,
    const float* __restrict__ W,        // [128][128] row-major (k, col)
    const float* __restrict__ bias,     // [128]
    float* __restrict__ C, int ldc,
    const float* __restrict__ Hprev, int ldh,
    const float* __restrict__ skipP,
    int M)
{
    __shared__ float shA[64][32];    // [row][k]   8 KB
    __shared__ float shW[32][128];   // [k][col]  16 KB

    const int tid  = threadIdx.x;
    const int r0   = blockIdx.x * 64;
    const int colg = tid & 31;       // 4 cols: colg*4 .. +3
    const int rowg = tid >> 5;       // 8 rows: rowg*8 .. +7

    float acc[8][4];
#pragma unroll
    for (int i = 0; i < 8; ++i)
#pragma unroll
        for (int j = 0; j < 4; ++j) acc[i][j] = 0.0f;

    for (int kc = 0; kc < 128; kc += 32) {
        // stage A chunk: 64 rows x 32 k  (512 float4, 2 per thread)
#pragma unroll
        for (int j = 0; j < 2; ++j) {
            int f   = j * 256 + tid;
            int row = f >> 3;
            int k4  = (f & 7) << 2;
            float4 v = make_float4(0.f, 0.f, 0.f, 0.f);
            int gr = r0 + row;
            if (gr < M) v = *(const float4*)(A + (size_t)gr * lda + kc + k4);
            if (ACT_IN == 1) {
                v.x = gelu_f(v.x); v.y = gelu_f(v.y);
                v.z = gelu_f(v.z); v.w = gelu_f(v.w);
            }
            *(float4*)&shA[row][k4] = v;
        }
        // stage W chunk: 32 k x 128 cols (1024 float4, 4 per thread)
#pragma unroll
        for (int j = 0; j < 4; ++j) {
            int f  = j * 256 + tid;
            int k  = f >> 5;
            int c4 = (f & 31) << 2;
            *(float4*)&shW[k][c4] = *(const float4*)(W + (size_t)(kc + k) * 128 + c4);
        }
        __syncthreads();

#pragma unroll
        for (int kk = 0; kk < 32; kk += 4) {
            float4 w0 = *(float4*)&shW[kk + 0][colg * 4];
            float4 w1 = *(float4*)&shW[kk + 1][colg * 4];
            float4 w2 = *(float4*)&shW[kk + 2][colg * 4];
            float4 w3 = *(float4*)&shW[kk + 3][colg * 4];
#pragma unroll
            for (int ri = 0; ri < 8; ++ri) {
                float4 a = *(float4*)&shA[rowg * 8 + ri][kk];
                acc[ri][0] = fmaf(a.x, w0.x, acc[ri][0]);
                acc[ri][1] = fmaf(a.x, w0.y, acc[ri][1]);
                acc[ri][2] = fmaf(a.x, w0.z, acc[ri][2]);
                acc[ri][3] = fmaf(a.x, w0.w, acc[ri][3]);
                acc[ri][0] = fmaf(a.y, w1.x, acc[ri][0]);
                acc[ri][1] = fmaf(a.y, w1.y, acc[ri][1]);
                acc[ri][2] = fmaf(a.y, w1.z, acc[ri][2]);
                acc[ri][3] = fmaf(a.y, w1.w, acc[ri][3]);
                acc[ri][0] = fmaf(a.z, w2.x, acc[ri][0]);
                acc[ri][1] = fmaf(a.z, w2.y, acc[ri][1]);
                acc[ri][2] = fmaf(a.z, w2.z, acc[ri][2]);
                acc[ri][3] = fmaf(a.z, w2.w, acc[ri][3]);
                acc[ri][0] = fmaf(a.w, w3.x, acc[ri][0]);
                acc[ri][1] = fmaf(a.w, w3.y, acc[ri][1]);
                acc[ri][2] = fmaf(a.w, w3.z, acc[ri][2]);
                acc[ri][3] = fmaf(a.w, w3.w, acc[ri][3]);
            }
        }
        __syncthreads();
    }

    float4 b4 = *(const float4*)(bias + colg * 4);
    float aa = 0.f, ab = 0.f;
    if (EPI == 2) {
        float sv = *skipP;
        aa = 1.0f / (1.0f + __expf(-sv));
        ab = 1.0f - aa;
    }
#pragma unroll
    for (int ri = 0; ri < 8; ++ri) {
        int gr = r0 + rowg * 8 + ri;
        if (gr >= M) continue;
        float4 o;
        o.x = acc[ri][0] + b4.x;
        o.y = acc[ri][1] + b4.y;
        o.z = acc[ri][2] + b4.z;
        o.w = acc[ri][3] + b4.w;
        if (EPI == 1) {
            o.x = fmaxf(o.x, 0.f); o.y = fmaxf(o.y, 0.f);
            o.z = fmaxf(o.z, 0.f); o.w = fmaxf(o.w, 0.f);
        }
        if (EPI == 2) {
            float4 hp = *(const float4*)(Hprev + (size_t)gr * ldh + colg * 4);
            o.x = aa * o.x + ab * hp.x;
            o.y = aa * o.y + ab * hp.y;
            o.z = aa * o.z + ab * hp.z;
            o.w = aa * o.w + ab * hp.w;
        }
        *(float4*)(C + (size_t)gr * ldc + colg * 4) = o;
    }
}

// ---------------------------------------------------------------------------
// Fused attention: one wave per destination node, online softmax over its
// CSR edge list. Lane = channel (h*32+d); pass A covers heads 0,1 (chan
// 0..63), pass B heads 2,3 (chan 64..127). Writes agg exactly once.
// ---------------------------------------------------------------------------
__global__ __launch_bounds__(256) void hgt_attn(
    const float* __restrict__ q,      // [Ndt][128]  (p_rel*scale folded into kr)
    const float* __restrict__ kr,     // [Nst][128]
    const float* __restrict__ vr,     // [Nst][128]
    const int* __restrict__ rowptr,   // [Ndt+1]
    const int* __restrict__ esrc,     // [E] src per CSR slot
    float* __restrict__ agg,          // [Ndt][128]
    int Ndt, int accumulate)
{
    const int wid  = threadIdx.x >> 6;
    const int lane = threadIdx.x & 63;
    const int n = blockIdx.x * 4 + wid;
    if (n >= Ndt) return;

    const int cA = lane;        // heads 0,1
    const int cB = lane + 64;   // heads 2,3

    const float qA = q[(size_t)n * 128 + cA];
    const float qB = q[(size_t)n * 128 + cB];

    const int p0 = rowptr[n], p1 = rowptr[n + 1];

    float mA = -INFINITY, mB = -INFINITY;
    float lA = 0.f, lB = 0.f;
    float accA = 0.f, accB = 0.f;

    for (int p = p0; p < p1; ++p) {
        const int s = esrc[p];
        const float* krow = kr + (size_t)s * 128;
        const float* vrow = vr + (size_t)s * 128;
        float aA = qA * krow[cA];
        float aB = qB * krow[cB];
#pragma unroll
        for (int off = 16; off > 0; off >>= 1) {
            aA += __shfl_xor(aA, off, 64);
            aB += __shfl_xor(aB, off, 64);
        }
        // aA = alpha for head (lane>>5); aB for head (lane>>5)+2
        float nmA = fmaxf(mA, aA);
        float sclA = __expf(mA - nmA);      // 0 on first iteration (mA=-inf)
        float wA = __expf(aA - nmA);
        lA = lA * sclA + wA;
        accA = accA * sclA + wA * vrow[cA];
        mA = nmA;

        float nmB = fmaxf(mB, aB);
        float sclB = __expf(mB - nmB);
        float wB = __expf(aB - nmB);
        lB = lB * sclB + wB;
        accB = accB * sclB + wB * vrow[cB];
        mB = nmB;
    }

    const float oA = accA / (lA + 1e-16f);
    const float oB = accB / (lB + 1e-16f);
    const size_t ob = (size_t)n * 128;
    if (accumulate) {
        agg[ob + cA] += oA;
        agg[ob + cB] += oB;
    } else {
        agg[ob + cA] = oA;
        agg[ob + cB] = oB;
    }
}

// ---------------------------------------------------------------------------
// Combined relation weights: Wc[c][h*32+e] = sum_d Wsrc[c][h*32+d]*rel[h][d][e]
// key side additionally scaled by p_rel[h]/sqrt(D). grid = (65, 12).
// ---------------------------------------------------------------------------
__global__ void hgt_makecw(
    const float* __restrict__ Wk, const float* __restrict__ bk,
    const float* __restrict__ Wv, const float* __restrict__ bv,
    const float* __restrict__ a_rel, const float* __restrict__ m_rel,
    const float* __restrict__ p_rel,
    float* __restrict__ cw, float* __restrict__ cb)
{
    const int y = blockIdx.y;                 // 0..11 = l*6 + r*2 + kv
    const int l = y / 6, rem = y % 6, r = rem >> 1, kv = rem & 1;
    const int st = (r == 0) ? 0 : 1;
    const float* Wsrc = (kv ? Wv : Wk) + (size_t)(l * 2 + st) * 16384;
    const float* bsrc = (kv ? bv : bk) + (l * 2 + st) * 128;
    const float* rel  = (kv ? m_rel : a_rel) + (size_t)(l * 3 + r) * 4096;

    const int idx = blockIdx.x * 256 + threadIdx.x;
    if (idx < 16384) {
        const int c = idx >> 7, o = idx & 127, h = o >> 5, e = o & 31;
        const float fac = kv ? 1.0f
                             : p_rel[(l * 3 + r) * 4 + h] * 0.17677669529663687f;
        const float* wrow = Wsrc + (size_t)c * 128 + h * 32;
        const float* rcol = rel + h * 1024 + e;
        float s = 0.f;
#pragma unroll
        for (int d = 0; d < 32; ++d) s = fmaf(wrow[d], rcol[d * 32], s);
        cw[(size_t)y * 16384 + idx] = s * fac;
    } else if (idx < 16512) {
        const int o = idx - 16384, h = o >> 5, e = o & 31;
        const float fac = kv ? 1.0f
                             : p_rel[(l * 3 + r) * 4 + h] * 0.17677669529663687f;
        const float* brow = bsrc + h * 32;
        const float* rcol = rel + h * 1024 + e;
        float s = 0.f;
#pragma unroll
        for (int d = 0; d < 32; ++d) s = fmaf(brow[d], rcol[d * 32], s);
        cb[y * 128 + o] = s * fac;
    }
}

// --------------------------- CSR construction ------------------------------
__global__ void hgt_hist(const int* __restrict__ dst, int E, int* __restrict__ deg)
{
    int e = blockIdx.x * 256 + threadIdx.x;
    if (e < E) atomicAdd(&deg[dst[e]], 1);
}

__global__ void hgt_scan1(const int* __restrict__ in, int* __restrict__ out,
                          int* __restrict__ bsums, int n)
{
    __shared__ int s[512];
    const int tid = threadIdx.x;
    const int i = blockIdx.x * 512 + tid;
    int v = (i < n) ? in[i] : 0;
    s[tid] = v;
    __syncthreads();
    for (int off = 1; off < 512; off <<= 1) {
        int t = (tid >= off) ? s[tid - off] : 0;
        __syncthreads();
        s[tid] += t;
        __syncthreads();
    }
    if (i < n) out[i] = s[tid] - v;      // exclusive
    if (tid == 511) bsums[blockIdx.x] = s[511];
}

__global__ void hgt_scan2(int* __restrict__ bsums, int nb)
{
    if (threadIdx.x == 0) {
        int run = 0;
        for (int b = 0; b < nb; ++b) { int t = bsums[b]; bsums[b] = run; run += t; }
    }
}

__global__ void hgt_scan3(int* __restrict__ out, const int* __restrict__ bsums, int n)
{
    int i = blockIdx.x * 512 + threadIdx.x;
    if (i < n) out[i] += bsums[blockIdx.x];
}

__global__ void hgt_fill(const int* __restrict__ src, const int* __restrict__ dst, int E,
                         const int* __restrict__ rowptr, int* __restrict__ cnt,
                         int* __restrict__ esrc)
{
    int e = blockIdx.x * 256 + threadIdx.x;
    if (e < E) {
        int d = dst[e];
        int r = atomicAdd(&cnt[d], 1);
        esrc[rowptr[d] + r] = src[e];
    }
}

// ---------------------------------------------------------------------------
extern "C" void kernel_launch(void* const* d_in, const int* in_sizes, int n_in,
                              void* d_out, int out_size, void* d_ws, size_t ws_size,
                              hipStream_t stream)
{
    const float* x0  = (const float*)d_in[0];
    const float* x1  = (const float*)d_in[1];
    const int* srcs[3] = {(const int*)d_in[2], (const int*)d_in[4], (const int*)d_in[6]};
    const int* dsts[3] = {(const int*)d_in[3], (const int*)d_in[5], (const int*)d_in[7]};
    const float* W_in = (const float*)d_in[8];
    const float* b_in = (const float*)d_in[9];
    const float* Wk = (const float*)d_in[10];
    const float* bk = (const float*)d_in[11];
    const float* Wq = (const float*)d_in[12];
    const float* bq = (const float*)d_in[13];
    const float* Wv = (const float*)d_in[14];
    const float* bv = (const float*)d_in[15];
    const float* Wa = (const float*)d_in[16];
    const float* ba = (const float*)d_in[17];
    const float* skip = (const float*)d_in[18];
    const float* a_rel = (const float*)d_in[19];
    const float* m_rel = (const float*)d_in[20];
    const float* p_rel = (const float*)d_in[21];

    const int N0 = in_sizes[0] / HID;   // 100000
    const int N1 = in_sizes[1] / HID;   // 50000
    const int E  = in_sizes[2];         // 200000
    const int Nt[2] = {N0, N1};
    float* out = (float*)d_out;
    const int OLD = 3 * HID;            // 384, output row stride

    // ---- workspace carve (256B aligned) ----
    char* p = (char*)d_ws;
    auto carve = [&](size_t bytes) -> char* {
        char* q = p;
        p += (bytes + 255) & ~(size_t)255;
        return q;
    };
    float* qbuf   = (float*)carve((size_t)(N0 + N1) * HID * 4);
    float* krbuf  = (float*)carve((size_t)N0 * HID * 4);
    float* vrbuf  = (float*)carve((size_t)N0 * HID * 4);
    float* aggbuf = (float*)carve((size_t)(N0 + N1) * HID * 4);
    float* cw     = (float*)carve((size_t)12 * 16384 * 4);
    float* cb     = (float*)carve((size_t)12 * 128 * 4);
    int* rowptr[3];
    rowptr[0] = (int*)carve((size_t)(N1 + 1) * 4);
    rowptr[1] = (int*)carve((size_t)(N0 + 1) * 4);
    rowptr[2] = (int*)carve((size_t)(N1 + 1) * 4);
    int* esrc[3];
    esrc[0] = (int*)carve((size_t)E * 4);
    esrc[1] = (int*)carve((size_t)E * 4);
    esrc[2] = (int*)carve((size_t)E * 4);
    int* deg   = (int*)carve((size_t)(N0 + 1) * 4);
    int* bsums = (int*)carve(1024 * 4);
    (void)ws_size; (void)n_in; (void)out_size;

    const int st_of[3] = {0, 1, 1}, dt_of[3] = {1, 0, 1};

    // ---- CSR per relation (edges identical across layers) ----
    for (int r = 0; r < 3; ++r) {
        const int Ndt = Nt[dt_of[r]];
        hipMemsetAsync(deg, 0, (size_t)(Ndt + 1) * 4, stream);
        hgt_hist<<<(E + 255) / 256, 256, 0, stream>>>(dsts[r], E, deg);
        const int n = Ndt + 1;
        const int nb = (n + 511) / 512;
        hgt_scan1<<<nb, 512, 0, stream>>>(deg, rowptr[r], bsums, n);
        hgt_scan2<<<1, 64, 0, stream>>>(bsums, nb);
        hgt_scan3<<<nb, 512, 0, stream>>>(rowptr[r], bsums, n);
        hipMemsetAsync(deg, 0, (size_t)Ndt * 4, stream);
        hgt_fill<<<(E + 255) / 256, 256, 0, stream>>>(srcs[r], dsts[r], E,
                                                      rowptr[r], deg, esrc[r]);
    }

    // ---- combined relation weights ----
    hgt_makecw<<<dim3(65, 12), 256, 0, stream>>>(Wk, bk, Wv, bv, a_rel, m_rel,
                                                 p_rel, cw, cb);

    auto g = [](int M) { return (M + 63) / 64; };

    // ---- initial projection: h0 -> d_out columns [0:128) ----
    hgt_gemm128<0, 1><<<g(N0), 256, 0, stream>>>(x0, HID, W_in, b_in,
                                                 out, OLD, nullptr, 0, nullptr, N0);
    hgt_gemm128<0, 1><<<g(N1), 256, 0, stream>>>(x1, HID, W_in + 16384, b_in + 128,
                                                 out + (size_t)N0 * OLD, OLD,
                                                 nullptr, 0, nullptr, N1);

    for (int l = 0; l < 2; ++l) {
        const float* h[2] = { out + (size_t)l * HID,
                              out + (size_t)N0 * OLD + (size_t)l * HID };
        float* qb[2]   = { qbuf, qbuf + (size_t)N0 * HID };
        float* aggb[2] = { aggbuf, aggbuf + (size_t)N0 * HID };

        for (int t = 0; t < 2; ++t)
            hgt_gemm128<0, 0><<<g(Nt[t]), 256, 0, stream>>>(
                h[t], OLD, Wq + (size_t)(l * 2 + t) * 16384, bq + (l * 2 + t) * 128,
                qb[t], HID, nullptr, 0, nullptr, Nt[t]);

        for (int r = 0; r < 3; ++r) {
            const int st = st_of[r], dt = dt_of[r];
            const int slot = l * 6 + r * 2;
            hgt_gemm128<0, 0><<<g(Nt[st]), 256, 0, stream>>>(
                h[st], OLD, cw + (size_t)slot * 16384, cb + slot * 128,
                krbuf, HID, nullptr, 0, nullptr, Nt[st]);
            hgt_gemm128<0, 0><<<g(Nt[st]), 256, 0, stream>>>(
                h[st], OLD, cw + (size_t)(slot + 1) * 16384, cb + (slot + 1) * 128,
                vrbuf, HID, nullptr, 0, nullptr, Nt[st]);
            hgt_attn<<<(Nt[dt] + 3) / 4, 256, 0, stream>>>(
                qb[dt], krbuf, vrbuf, rowptr[r], esrc[r],
                aggb[dt], Nt[dt], (r == 2) ? 1 : 0);
        }

        for (int t = 0; t < 2; ++t) {
            float* Cout = (t ? out + (size_t)N0 * OLD : out) + (size_t)(l + 1) * HID;
            hgt_gemm128<1, 2><<<g(Nt[t]), 256, 0, stream>>>(
                aggb[t], HID, Wa + (size_t)(l * 2 + t) * 16384, ba + (l * 2 + t) * 128,
                Cout, OLD, h[t], OLD, skip + l * 2 + t, Nt[t]);
        }
    }
}

// Round 2
// 1097.820 us; speedup vs baseline: 1.4422x; 1.4422x over previous
//
#include <hip/hip_runtime.h>
#include <math.h>

// ---------------------------------------------------------------------------
// HGT on MI355X — round 2: bf16 MFMA GEMMs (B-in-registers, frag-packed
// weights, no LDS), bf16 intermediates, gelu fused into attention epilogue.
// ---------------------------------------------------------------------------

#define HID 128
#define OLD 384   // d_out row stride = 3*HID

typedef __attribute__((ext_vector_type(8))) short short8;
typedef __attribute__((ext_vector_type(4))) float f32x4;

__device__ __forceinline__ unsigned short f2b(float f) {
    unsigned u = __float_as_uint(f);
    u += 0x7fffu + ((u >> 16) & 1u);          // RNE
    return (unsigned short)(u >> 16);
}
__device__ __forceinline__ float b2f(unsigned short s) {
    return __uint_as_float((unsigned)s << 16);
}
__device__ __forceinline__ float gelu_f(float x) {
    return 0.5f * x * (1.0f + erff(x * 0.70710678118654752f));
}

// ---------------------------------------------------------------------------
// MFMA GEMM: C[M, ntiles*128] = epi(A[M,128] @ W[128, ntiles*128] + bias)
// Bp is frag-packed bf16: per 128x128 col-block: [nt(8)][kt(4)][lane(64)][j(8)]
//   with n = nt*16 + (lane&15), k = kt*32 + (lane>>4)*8 + j.
// Block = 256 thr (4 waves, 2x2 of 64x64), tile 128 rows x 128 cols, K=128.
// AFP32: A is fp32 (convert on load) else bf16.
// EPI 0: store bf16 to Cb (ldcb = total ncols), col base = blockIdx.x*128
// EPI 1: relu; store fp32 to Cf (ldcf) AND bf16 to Cb (ld=128)  [in-proj]
// EPI 2: skip-mix with Hb (bf16, ld=128); store fp32 Cf + bf16 Cb [out-proj]
// ---------------------------------------------------------------------------
template <int AFP32, int EPI>
__global__ __launch_bounds__(256) void mfma_gemm(
    const void* __restrict__ Aptr, int lda,
    const unsigned short* __restrict__ Bp,
    const float* __restrict__ biasP,
    unsigned short* __restrict__ Cb, int ldcb,
    float* __restrict__ Cf, int ldcf,
    const unsigned short* __restrict__ Hb,
    const float* __restrict__ skipP,
    int M)
{
    const int tid  = threadIdx.x;
    const int wid  = tid >> 6;
    const int lane = tid & 63;
    const int mwave = (wid >> 1) * 64;
    const int nwave = (wid & 1) * 64;
    const int lm = lane & 15;
    const int kq = lane >> 4;
    const int r0 = blockIdx.y * 128;
    const int ct = blockIdx.x;

    // ---- B fragments (held in registers for the whole block) ----
    short8 bf[4][4];
    const unsigned short* bbase = Bp + (size_t)ct * 16384;
#pragma unroll
    for (int ni = 0; ni < 4; ++ni) {
        const int nt = (nwave >> 4) + ni;
#pragma unroll
        for (int kt = 0; kt < 4; ++kt)
            bf[ni][kt] = *(const short8*)(bbase + (((nt * 4 + kt) * 64 + lane) << 3));
    }

    f32x4 acc[4][4];
#pragma unroll
    for (int mi = 0; mi < 4; ++mi)
#pragma unroll
        for (int ni = 0; ni < 4; ++ni)
            acc[mi][ni] = (f32x4){0.f, 0.f, 0.f, 0.f};

#pragma unroll
    for (int mi = 0; mi < 4; ++mi) {
        int row = r0 + mwave + mi * 16 + lm;
        row = (row < M) ? row : (M - 1);
        short8 af[4];
        if (AFP32) {
            const float* ar = (const float*)Aptr + (size_t)row * lda;
#pragma unroll
            for (int kt = 0; kt < 4; ++kt) {
                float4 v0 = *(const float4*)(ar + kt * 32 + kq * 8);
                float4 v1 = *(const float4*)(ar + kt * 32 + kq * 8 + 4);
                short8 t;
                t[0] = (short)f2b(v0.x); t[1] = (short)f2b(v0.y);
                t[2] = (short)f2b(v0.z); t[3] = (short)f2b(v0.w);
                t[4] = (short)f2b(v1.x); t[5] = (short)f2b(v1.y);
                t[6] = (short)f2b(v1.z); t[7] = (short)f2b(v1.w);
                af[kt] = t;
            }
        } else {
            const unsigned short* ar = (const unsigned short*)Aptr + (size_t)row * lda;
#pragma unroll
            for (int kt = 0; kt < 4; ++kt)
                af[kt] = *(const short8*)(ar + kt * 32 + kq * 8);
        }
#pragma unroll
        for (int ni = 0; ni < 4; ++ni)
#pragma unroll
            for (int kt = 0; kt < 4; ++kt)
                acc[mi][ni] = __builtin_amdgcn_mfma_f32_16x16x32_bf16(
                    af[kt], bf[ni][kt], acc[mi][ni], 0, 0, 0);
    }

    // ---- epilogue ----
    float biasv[4];
#pragma unroll
    for (int ni = 0; ni < 4; ++ni)
        biasv[ni] = biasP[ct * 128 + nwave + ni * 16 + lm];

    float aa = 0.f, ab = 0.f;
    if (EPI == 2) {
        const float sv = *skipP;
        aa = 1.0f / (1.0f + __expf(-sv));
        ab = 1.0f - aa;
    }

#pragma unroll
    for (int mi = 0; mi < 4; ++mi) {
#pragma unroll
        for (int ni = 0; ni < 4; ++ni) {
            const int col = nwave + ni * 16 + lm;
#pragma unroll
            for (int r = 0; r < 4; ++r) {
                const int grow = r0 + mwave + mi * 16 + kq * 4 + r;
                if (grow >= M) continue;
                float v = acc[mi][ni][r] + biasv[ni];
                if (EPI == 0) {
                    Cb[(size_t)grow * ldcb + ct * 128 + col] = f2b(v);
                } else if (EPI == 1) {
                    v = fmaxf(v, 0.f);
                    Cf[(size_t)grow * ldcf + col] = v;
                    Cb[(size_t)grow * 128 + col] = f2b(v);
                } else {
                    const float hp = b2f(Hb[(size_t)grow * 128 + col]);
                    const float o = aa * v + ab * hp;
                    Cf[(size_t)grow * ldcf + col] = o;
                    Cb[(size_t)grow * 128 + col] = f2b(o);
                }
            }
        }
    }
}

// ---------------------------------------------------------------------------
// Fused attention (bf16 in/out): one wave per dst node, online softmax over
// CSR edges. ACCUM: add into existing agg. GELU: apply gelu on final write.
// ---------------------------------------------------------------------------
template <int ACCUM, int GELU>
__global__ __launch_bounds__(256) void hgt_attn(
    const unsigned short* __restrict__ q, int ldq,
    const unsigned short* __restrict__ kr, int ldk,
    const unsigned short* __restrict__ vr, int ldv,
    const int* __restrict__ rowptr,
    const int* __restrict__ esrc,
    unsigned short* __restrict__ agg,
    int Ndt)
{
    const int wid  = threadIdx.x >> 6;
    const int lane = threadIdx.x & 63;
    const int n = blockIdx.x * 4 + wid;
    if (n >= Ndt) return;

    const int cA = lane;
    const int cB = lane + 64;

    const float qA = b2f(q[(size_t)n * ldq + cA]);
    const float qB = b2f(q[(size_t)n * ldq + cB]);

    const int p0 = rowptr[n], p1 = rowptr[n + 1];

    float mA = -INFINITY, mB = -INFINITY;
    float lA = 0.f, lB = 0.f;
    float accA = 0.f, accB = 0.f;

    for (int p = p0; p < p1; ++p) {
        const int s = esrc[p];
        const unsigned short* krow = kr + (size_t)s * ldk;
        const unsigned short* vrow = vr + (size_t)s * ldv;
        float aA = qA * b2f(krow[cA]);
        float aB = qB * b2f(krow[cB]);
#pragma unroll
        for (int off = 16; off > 0; off >>= 1) {
            aA += __shfl_xor(aA, off, 64);
            aB += __shfl_xor(aB, off, 64);
        }
        float nmA = fmaxf(mA, aA);
        float sclA = __expf(mA - nmA);
        float wA = __expf(aA - nmA);
        lA = lA * sclA + wA;
        accA = accA * sclA + wA * b2f(vrow[cA]);
        mA = nmA;

        float nmB = fmaxf(mB, aB);
        float sclB = __expf(mB - nmB);
        float wB = __expf(aB - nmB);
        lB = lB * sclB + wB;
        accB = accB * sclB + wB * b2f(vrow[cB]);
        mB = nmB;
    }

    float oA = accA / (lA + 1e-16f);
    float oB = accB / (lB + 1e-16f);
    const size_t ob = (size_t)n * 128;
    if (ACCUM) {
        oA += b2f(agg[ob + cA]);
        oB += b2f(agg[ob + cB]);
    }
    if (GELU) { oA = gelu_f(oA); oB = gelu_f(oB); }
    agg[ob + cA] = f2b(oA);
    agg[ob + cB] = f2b(oB);
}

// ---------------------------------------------------------------------------
// Combined relation weights (fp32): cw[y][c][h*32+e], y = l*6 + r*2 + kv.
// Key side scaled by p_rel[h]/sqrt(D).
// ---------------------------------------------------------------------------
__global__ void hgt_makecw(
    const float* __restrict__ Wk, const float* __restrict__ bk,
    const float* __restrict__ Wv, const float* __restrict__ bv,
    const float* __restrict__ a_rel, const float* __restrict__ m_rel,
    const float* __restrict__ p_rel,
    float* __restrict__ cw, float* __restrict__ cb)
{
    const int y = blockIdx.y;
    const int l = y / 6, rem = y % 6, r = rem >> 1, kv = rem & 1;
    const int st = (r == 0) ? 0 : 1;
    const float* Wsrc = (kv ? Wv : Wk) + (size_t)(l * 2 + st) * 16384;
    const float* bsrc = (kv ? bv : bk) + (l * 2 + st) * 128;
    const float* rel  = (kv ? m_rel : a_rel) + (size_t)(l * 3 + r) * 4096;

    const int idx = blockIdx.x * 256 + threadIdx.x;
    if (idx < 16384) {
        const int c = idx >> 7, o = idx & 127, h = o >> 5, e = o & 31;
        const float fac = kv ? 1.0f
                             : p_rel[(l * 3 + r) * 4 + h] * 0.17677669529663687f;
        const float* wrow = Wsrc + (size_t)c * 128 + h * 32;
        const float* rcol = rel + h * 1024 + e;
        float s = 0.f;
#pragma unroll
        for (int d = 0; d < 32; ++d) s = fmaf(wrow[d], rcol[d * 32], s);
        cw[(size_t)y * 16384 + idx] = s * fac;
    } else if (idx < 16512) {
        const int o = idx - 16384, h = o >> 5, e = o & 31;
        const float fac = kv ? 1.0f
                             : p_rel[(l * 3 + r) * 4 + h] * 0.17677669529663687f;
        const float* brow = bsrc + h * 32;
        const float* rcol = rel + h * 1024 + e;
        float s = 0.f;
#pragma unroll
        for (int d = 0; d < 32; ++d) s = fmaf(brow[d], rcol[d * 32], s);
        cb[y * 128 + o] = s * fac;
    }
}

// ---------------------------------------------------------------------------
// Weight pack: 22 blocks of 128x128 fp32 -> bf16 MFMA-B-fragment order.
// Block order: [Win0,Win1, Wq00,cw0,cw1, Wq01,cw2,cw3,cw4,cw5, Wa00,Wa01,
//               Wq10,cw6,cw7, Wq11,cw8,cw9,cw10,cw11, Wa10,Wa11]
// ---------------------------------------------------------------------------
__device__ __forceinline__ const float* pack_src(
    int bid, const float* W_in, const float* Wq, const float* Wa, const float* cw)
{
    if (bid < 2)        return W_in + (size_t)bid * 16384;
    if (bid == 2)       return Wq;
    if (bid <= 4)       return cw + (size_t)(bid - 3) * 16384;
    if (bid == 5)       return Wq + 16384;
    if (bid <= 9)       return cw + (size_t)(bid - 4) * 16384;      // cw2..cw5
    if (bid == 10)      return Wa;
    if (bid == 11)      return Wa + 16384;
    if (bid == 12)      return Wq + 2 * 16384;
    if (bid <= 14)      return cw + (size_t)(bid - 7) * 16384;      // cw6,cw7
    if (bid == 15)      return Wq + 3 * 16384;
    if (bid <= 19)      return cw + (size_t)(bid - 8) * 16384;      // cw8..cw11
    return Wa + (size_t)(bid - 18) * 16384;                          // Wa2,Wa3
}
__device__ __forceinline__ const float* pack_bsrc(
    int bid, const float* b_in, const float* bq, const float* ba, const float* cb)
{
    if (bid < 2)        return b_in + bid * 128;
    if (bid == 2)       return bq;
    if (bid <= 4)       return cb + (bid - 3) * 128;
    if (bid == 5)       return bq + 128;
    if (bid <= 9)       return cb + (bid - 4) * 128;
    if (bid == 10)      return ba;
    if (bid == 11)      return ba + 128;
    if (bid == 12)      return bq + 2 * 128;
    if (bid <= 14)      return cb + (bid - 7) * 128;
    if (bid == 15)      return bq + 3 * 128;
    if (bid <= 19)      return cb + (bid - 8) * 128;
    return ba + (bid - 18) * 128;
}

__global__ void hgt_pack(const float* __restrict__ W_in, const float* __restrict__ Wq,
                         const float* __restrict__ Wa, const float* __restrict__ cw,
                         const float* __restrict__ b_in, const float* __restrict__ bq,
                         const float* __restrict__ ba, const float* __restrict__ cb,
                         unsigned short* __restrict__ Bp, float* __restrict__ bp)
{
    const int bid = blockIdx.x;
    const float* src  = pack_src(bid, W_in, Wq, Wa, cw);
    unsigned short* dst = Bp + (size_t)bid * 16384;
    for (int i = threadIdx.x; i < 16384; i += 256) {
        const int nt = i >> 11, kt = (i >> 9) & 3, lane = (i >> 3) & 63, j = i & 7;
        const int n = nt * 16 + (lane & 15);
        const int k = kt * 32 + (lane >> 4) * 8 + j;
        dst[i] = f2b(src[k * 128 + n]);
    }
    if (threadIdx.x < 128) {
        const float* bsrc = pack_bsrc(bid, b_in, bq, ba, cb);
        bp[bid * 128 + threadIdx.x] = bsrc[threadIdx.x];
    }
}

// --------------------------- CSR construction ------------------------------
__global__ void hgt_hist(const int* __restrict__ dst, int E, int* __restrict__ deg)
{
    int e = blockIdx.x * 256 + threadIdx.x;
    if (e < E) atomicAdd(&deg[dst[e]], 1);
}

__global__ void hgt_scan1(const int* __restrict__ in, int* __restrict__ out,
                          int* __restrict__ bsums, int n)
{
    __shared__ int s[512];
    const int tid = threadIdx.x;
    const int i = blockIdx.x * 512 + tid;
    int v = (i < n) ? in[i] : 0;
    s[tid] = v;
    __syncthreads();
    for (int off = 1; off < 512; off <<= 1) {
        int t = (tid >= off) ? s[tid - off] : 0;
        __syncthreads();
        s[tid] += t;
        __syncthreads();
    }
    if (i < n) out[i] = s[tid] - v;
    if (tid == 511) bsums[blockIdx.x] = s[511];
}

__global__ void hgt_scan2(int* __restrict__ bsums, int nb)
{
    if (threadIdx.x == 0) {
        int run = 0;
        for (int b = 0; b < nb; ++b) { int t = bsums[b]; bsums[b] = run; run += t; }
    }
}

__global__ void hgt_scan3(int* __restrict__ out, const int* __restrict__ bsums, int n)
{
    int i = blockIdx.x * 512 + threadIdx.x;
    if (i < n) out[i] += bsums[blockIdx.x];
}

__global__ void hgt_fill(const int* __restrict__ src, const int* __restrict__ dst, int E,
                         const int* __restrict__ rowptr, int* __restrict__ cnt,
                         int* __restrict__ esrc)
{
    int e = blockIdx.x * 256 + threadIdx.x;
    if (e < E) {
        int d = dst[e];
        int r = atomicAdd(&cnt[d], 1);
        esrc[rowptr[d] + r] = src[e];
    }
}

// ---------------------------------------------------------------------------
extern "C" void kernel_launch(void* const* d_in, const int* in_sizes, int n_in,
                              void* d_out, int out_size, void* d_ws, size_t ws_size,
                              hipStream_t stream)
{
    const float* x0  = (const float*)d_in[0];
    const float* x1  = (const float*)d_in[1];
    const int* srcs[3] = {(const int*)d_in[2], (const int*)d_in[4], (const int*)d_in[6]};
    const int* dsts[3] = {(const int*)d_in[3], (const int*)d_in[5], (const int*)d_in[7]};
    const float* W_in = (const float*)d_in[8];
    const float* b_in = (const float*)d_in[9];
    const float* Wk = (const float*)d_in[10];
    const float* bk = (const float*)d_in[11];
    const float* Wq = (const float*)d_in[12];
    const float* bq = (const float*)d_in[13];
    const float* Wv = (const float*)d_in[14];
    const float* bv = (const float*)d_in[15];
    const float* Wa = (const float*)d_in[16];
    const float* ba = (const float*)d_in[17];
    const float* skip = (const float*)d_in[18];
    const float* a_rel = (const float*)d_in[19];
    const float* m_rel = (const float*)d_in[20];
    const float* p_rel = (const float*)d_in[21];

    const int N0 = in_sizes[0] / HID;   // 100000
    const int N1 = in_sizes[1] / HID;   // 50000
    const int E  = in_sizes[2];         // 200000
    const int Nt[2] = {N0, N1};
    float* out = (float*)d_out;
    (void)n_in; (void)out_size; (void)ws_size;

    // ---- workspace carve (256B aligned) ----
    char* p = (char*)d_ws;
    auto carve = [&](size_t bytes) -> char* {
        char* q = p;
        p += (bytes + 255) & ~(size_t)255;
        return q;
    };
    unsigned short* hbf  = (unsigned short*)carve((size_t)(N0 + N1) * 128 * 2);
    unsigned short* qkv0 = (unsigned short*)carve((size_t)N0 * 384 * 2);
    unsigned short* qkv1 = (unsigned short*)carve((size_t)N1 * 640 * 2);
    unsigned short* agg  = (unsigned short*)carve((size_t)(N0 + N1) * 128 * 2);
    float* cw = (float*)carve((size_t)12 * 16384 * 4);
    float* cb = (float*)carve((size_t)12 * 128 * 4);
    unsigned short* packW = (unsigned short*)carve((size_t)22 * 16384 * 2);
    float* packb = (float*)carve((size_t)22 * 128 * 4);
    int* rowptr[3];
    rowptr[0] = (int*)carve((size_t)(N1 + 1) * 4);
    rowptr[1] = (int*)carve((size_t)(N0 + 1) * 4);
    rowptr[2] = (int*)carve((size_t)(N1 + 1) * 4);
    int* esrc[3];
    esrc[0] = (int*)carve((size_t)E * 4);
    esrc[1] = (int*)carve((size_t)E * 4);
    esrc[2] = (int*)carve((size_t)E * 4);
    int* deg   = (int*)carve((size_t)(N0 + 1) * 4);
    int* bsums = (int*)carve(1024 * 4);

    unsigned short* hbf1 = hbf + (size_t)N0 * 128;
    unsigned short* agg0 = agg;
    unsigned short* agg1 = agg + (size_t)N0 * 128;

    const int dt_of[3] = {1, 0, 1};

    // ---- CSR per relation ----
    for (int r = 0; r < 3; ++r) {
        const int Ndt = Nt[dt_of[r]];
        hipMemsetAsync(deg, 0, (size_t)(Ndt + 1) * 4, stream);
        hgt_hist<<<(E + 255) / 256, 256, 0, stream>>>(dsts[r], E, deg);
        const int n = Ndt + 1;
        const int nb = (n + 511) / 512;
        hgt_scan1<<<nb, 512, 0, stream>>>(deg, rowptr[r], bsums, n);
        hgt_scan2<<<1, 64, 0, stream>>>(bsums, nb);
        hgt_scan3<<<nb, 512, 0, stream>>>(rowptr[r], bsums, n);
        hipMemsetAsync(deg, 0, (size_t)Ndt * 4, stream);
        hgt_fill<<<(E + 255) / 256, 256, 0, stream>>>(srcs[r], dsts[r], E,
                                                      rowptr[r], deg, esrc[r]);
    }

    // ---- weights: combine + frag-pack ----
    hgt_makecw<<<dim3(65, 12), 256, 0, stream>>>(Wk, bk, Wv, bv, a_rel, m_rel,
                                                 p_rel, cw, cb);
    hgt_pack<<<22, 256, 0, stream>>>(W_in, Wq, Wa, cw, b_in, bq, ba, cb,
                                     packW, packb);

    auto mb = [](int M) { return (M + 127) / 128; };

    // ---- in-proj: h0 -> d_out cols [0:128) + hbf ----
    mfma_gemm<1, 1><<<dim3(1, mb(N0)), 256, 0, stream>>>(
        x0, 128, packW + 0 * 16384, packb + 0 * 128,
        hbf, 128, out, OLD, nullptr, nullptr, N0);
    mfma_gemm<1, 1><<<dim3(1, mb(N1)), 256, 0, stream>>>(
        x1, 128, packW + 1 * 16384, packb + 1 * 128,
        hbf1, 128, out + (size_t)N0 * OLD, OLD, nullptr, nullptr, N1);

    for (int l = 0; l < 2; ++l) {
        const int qkv0_blk = l ? 12 : 2;
        const int qkv1_blk = l ? 15 : 5;
        const int out0_blk = l ? 20 : 10;
        const int out1_blk = l ? 21 : 11;

        // fused q|kr|vr GEMMs
        mfma_gemm<0, 0><<<dim3(3, mb(N0)), 256, 0, stream>>>(
            hbf, 128, packW + (size_t)qkv0_blk * 16384, packb + qkv0_blk * 128,
            qkv0, 384, nullptr, 0, nullptr, nullptr, N0);
        mfma_gemm<0, 0><<<dim3(5, mb(N1)), 256, 0, stream>>>(
            hbf1, 128, packW + (size_t)qkv1_blk * 16384, packb + qkv1_blk * 128,
            qkv1, 640, nullptr, 0, nullptr, nullptr, N1);

        // r0: src t0 -> dst t1 (no gelu yet; r2 accumulates on top)
        hgt_attn<0, 0><<<(N1 + 3) / 4, 256, 0, stream>>>(
            qkv1, 640, qkv0 + 128, 384, qkv0 + 256, 384,
            rowptr[0], esrc[0], agg1, N1);
        // r1: src t1 -> dst t0 (final for t0 -> gelu)
        hgt_attn<0, 1><<<(N0 + 3) / 4, 256, 0, stream>>>(
            qkv0, 384, qkv1 + 128, 640, qkv1 + 256, 640,
            rowptr[1], esrc[1], agg0, N0);
        // r2: src t1 -> dst t1 (accumulate + gelu)
        hgt_attn<1, 1><<<(N1 + 3) / 4, 256, 0, stream>>>(
            qkv1, 640, qkv1 + 384, 640, qkv1 + 512, 640,
            rowptr[2], esrc[2], agg1, N1);

        // out-proj + skip-mix -> d_out cols [(l+1)*128 : (l+2)*128) + hbf
        mfma_gemm<0, 2><<<dim3(1, mb(N0)), 256, 0, stream>>>(
            agg0, 128, packW + (size_t)out0_blk * 16384, packb + out0_blk * 128,
            hbf, 128, out + (size_t)(l + 1) * 128, OLD,
            hbf, skip + l * 2 + 0, N0);
        mfma_gemm<0, 2><<<dim3(1, mb(N1)), 256, 0, stream>>>(
            agg1, 128, packW + (size_t)out1_blk * 16384, packb + out1_blk * 128,
            hbf1, 128, out + (size_t)N0 * OLD + (size_t)(l + 1) * 128, OLD,
            hbf1, skip + l * 2 + 1, N1);
    }
}

// Round 3
// 976.179 us; speedup vs baseline: 1.6219x; 1.1246x over previous
//
#include <hip/hip_runtime.h>
#include <math.h>

// ---------------------------------------------------------------------------
// HGT on MI355X — round 3.
//  * MFMA GEMMs with operands swapped (W as A-operand, activations as B):
//    D[outch][node] lets each lane pack 4 consecutive outch -> 8B/16B stores.
//  * CSR build fused across the 3 relations (6 dispatches total, parallel
//    block-sum scan — no serial single-thread scan).
//  * makecw folded into the pack kernel (combined rel weights on the fly).
//  * Attention: 2 channels per lane, r0+r2 fused for dst-type1.
// ---------------------------------------------------------------------------

#define HID 128
#define OLD 384   // d_out row stride = 3*HID

typedef __attribute__((ext_vector_type(8))) short short8;
typedef __attribute__((ext_vector_type(4))) float f32x4;

__device__ __forceinline__ unsigned short f2b(float f) {
    unsigned u = __float_as_uint(f);
    u += 0x7fffu + ((u >> 16) & 1u);          // RNE
    return (unsigned short)(u >> 16);
}
__device__ __forceinline__ unsigned pk2(float a, float b) {
    return (unsigned)f2b(a) | ((unsigned)f2b(b) << 16);
}
__device__ __forceinline__ float blo(unsigned u) { return __uint_as_float(u << 16); }
__device__ __forceinline__ float bhi(unsigned u) { return __uint_as_float(u & 0xffff0000u); }
__device__ __forceinline__ float b2f(unsigned short s) {
    return __uint_as_float((unsigned)s << 16);
}
__device__ __forceinline__ float gelu_f(float x) {
    return 0.5f * x * (1.0f + erff(x * 0.70710678118654752f));
}

// ---------------------------------------------------------------------------
// MFMA GEMM (transposed operands): D = W^T-as-A  x  activations-as-B.
// Wp frag-packed per 128x128 block: [mt(8)][kt(4)][lane(64)][j(8)],
//   m(outch) = mt*16 + (lane&15), k(inch) = kt*32 + (lane>>4)*8 + j.
// Activations: row-major [node][128] (bf16, or fp32 if AFP32).
// D mapping (16x16x32): node = lane&15, outch = (lane>>4)*4 + reg.
// Block 256 thr = 4 waves (2x2): 128 outch x 128 nodes; grid.x = col-blocks.
// EPI 0: bf16 -> Cb[node*ldcb + ct*128 + oc]           (qkv)
// EPI 1: relu; fp32 -> Cf[node*ldcf+oc], bf16 -> Cb[node*128+oc]   (in-proj)
// EPI 2: skip-mix with Hb (bf16,128); fp32 Cf + bf16 Cb            (out-proj)
// ---------------------------------------------------------------------------
template <int AFP32, int EPI>
__global__ __launch_bounds__(256) void mfma_gemm(
    const void* __restrict__ Aptr, int lda,
    const unsigned short* __restrict__ Wp,
    const float* __restrict__ biasP,
    unsigned short* __restrict__ Cb, int ldcb,
    float* __restrict__ Cf, int ldcf,
    const unsigned short* __restrict__ Hb,
    const float* __restrict__ skipP,
    int M)
{
    const int tid  = threadIdx.x;
    const int wid  = tid >> 6;
    const int lane = tid & 63;
    const int ow = (wid >> 1) * 64;     // outch offset in 128-block
    const int nw = (wid & 1) * 64;      // node offset in 128-tile
    const int lm = lane & 15;
    const int kq = lane >> 4;
    const int r0 = blockIdx.y * 128;
    const int ct = blockIdx.x;

    // ---- weight A-fragments, resident in registers ----
    short8 wf[4][4];
    const unsigned short* wbase = Wp + (size_t)ct * 16384;
#pragma unroll
    for (int mi = 0; mi < 4; ++mi) {
        const int mt = (ow >> 4) + mi;
#pragma unroll
        for (int kt = 0; kt < 4; ++kt)
            wf[mi][kt] = *(const short8*)(wbase + (((mt * 4 + kt) * 64 + lane) << 3));
    }

    f32x4 acc[4][4];    // [ni(node tile)][mi(outch tile)]
#pragma unroll
    for (int ni = 0; ni < 4; ++ni)
#pragma unroll
        for (int mi = 0; mi < 4; ++mi)
            acc[ni][mi] = (f32x4){0.f, 0.f, 0.f, 0.f};

#pragma unroll
    for (int ni = 0; ni < 4; ++ni) {
        int node = r0 + nw + ni * 16 + lm;
        node = (node < M) ? node : (M - 1);
        short8 bfr[4];
        if (AFP32) {
            const float* ar = (const float*)Aptr + (size_t)node * lda;
#pragma unroll
            for (int kt = 0; kt < 4; ++kt) {
                float4 v0 = *(const float4*)(ar + kt * 32 + kq * 8);
                float4 v1 = *(const float4*)(ar + kt * 32 + kq * 8 + 4);
                short8 t;
                t[0] = (short)f2b(v0.x); t[1] = (short)f2b(v0.y);
                t[2] = (short)f2b(v0.z); t[3] = (short)f2b(v0.w);
                t[4] = (short)f2b(v1.x); t[5] = (short)f2b(v1.y);
                t[6] = (short)f2b(v1.z); t[7] = (short)f2b(v1.w);
                bfr[kt] = t;
            }
        } else {
            const unsigned short* ar = (const unsigned short*)Aptr + (size_t)node * lda;
#pragma unroll
            for (int kt = 0; kt < 4; ++kt)
                bfr[kt] = *(const short8*)(ar + kt * 32 + kq * 8);
        }
#pragma unroll
        for (int kt = 0; kt < 4; ++kt)
#pragma unroll
            for (int mi = 0; mi < 4; ++mi)
                acc[ni][mi] = __builtin_amdgcn_mfma_f32_16x16x32_bf16(
                    wf[mi][kt], bfr[kt], acc[ni][mi], 0, 0, 0);
    }

    // ---- epilogue: lane owns 4 consecutive outch per (ni,mi) ----
    float4 b4[4];
#pragma unroll
    for (int mi = 0; mi < 4; ++mi)
        b4[mi] = *(const float4*)(biasP + ct * 128 + ow + mi * 16 + kq * 4);

    float aa = 0.f, ab = 0.f;
    if (EPI == 2) {
        const float sv = *skipP;
        aa = 1.0f / (1.0f + __expf(-sv));
        ab = 1.0f - aa;
    }

#pragma unroll
    for (int ni = 0; ni < 4; ++ni) {
        const int node = r0 + nw + ni * 16 + lm;
        if (node >= M) continue;
#pragma unroll
        for (int mi = 0; mi < 4; ++mi) {
            const int oc = ow + mi * 16 + kq * 4;
            float v0 = acc[ni][mi][0] + b4[mi].x;
            float v1 = acc[ni][mi][1] + b4[mi].y;
            float v2 = acc[ni][mi][2] + b4[mi].z;
            float v3 = acc[ni][mi][3] + b4[mi].w;
            if (EPI == 1) {
                v0 = fmaxf(v0, 0.f); v1 = fmaxf(v1, 0.f);
                v2 = fmaxf(v2, 0.f); v3 = fmaxf(v3, 0.f);
            }
            if (EPI == 2) {
                uint2 hp = *(const uint2*)(Hb + (size_t)node * 128 + oc);
                v0 = aa * v0 + ab * blo(hp.x);
                v1 = aa * v1 + ab * bhi(hp.x);
                v2 = aa * v2 + ab * blo(hp.y);
                v3 = aa * v3 + ab * bhi(hp.y);
            }
            if (EPI != 0) {
                *(float4*)(Cf + (size_t)node * ldcf + oc) =
                    make_float4(v0, v1, v2, v3);
                *(uint2*)(Cb + (size_t)node * 128 + oc) =
                    make_uint2(pk2(v0, v1), pk2(v2, v3));
            } else {
                *(uint2*)(Cb + (size_t)node * ldcb + ct * 128 + oc) =
                    make_uint2(pk2(v0, v1), pk2(v2, v3));
            }
        }
    }
}

// ---------------------------------------------------------------------------
// Attention, 2 channels per lane (lane c -> channels 2c,2c+1; head = lane>>4).
// One wave per dst node; online softmax over CSR edges; gelu on final write.
// ---------------------------------------------------------------------------
__device__ __forceinline__ void attn_loop(
    const unsigned short* __restrict__ kv, size_t ldkv, int kof, int vof,
    const int* __restrict__ rowptr, const int* __restrict__ esrc,
    int n, int lane, float q0, float q1,
    float& o0, float& o1)
{
    const int p0 = rowptr[n], p1 = rowptr[n + 1];
    float m = -INFINITY, l = 0.f, a0 = 0.f, a1 = 0.f;
    for (int p = p0; p < p1; ++p) {
        const int s = esrc[p];
        const size_t sb = (size_t)s * ldkv;
        const unsigned kp = *(const unsigned*)(kv + sb + kof + 2 * lane);
        const unsigned vp = *(const unsigned*)(kv + sb + vof + 2 * lane);
        float al = q0 * blo(kp) + q1 * bhi(kp);
        al += __shfl_xor(al, 1, 64);
        al += __shfl_xor(al, 2, 64);
        al += __shfl_xor(al, 4, 64);
        al += __shfl_xor(al, 8, 64);
        const float nm  = fmaxf(m, al);
        const float scl = __expf(m - nm);
        const float w   = __expf(al - nm);
        l  = l * scl + w;
        a0 = a0 * scl + w * blo(vp);
        a1 = a1 * scl + w * bhi(vp);
        m  = nm;
    }
    const float inv = 1.0f / (l + 1e-16f);
    o0 = a0 * inv;
    o1 = a1 * inv;
}

// dst type0: relation 1 only (src t1)
__global__ __launch_bounds__(256) void hgt_attn_t0(
    const unsigned short* __restrict__ qkv0,
    const unsigned short* __restrict__ qkv1,
    const int* __restrict__ rowptr, const int* __restrict__ esrc,
    unsigned short* __restrict__ agg, int N)
{
    const int wid = threadIdx.x >> 6, lane = threadIdx.x & 63;
    const int n = blockIdx.x * 4 + wid;
    if (n >= N) return;
    const unsigned qp = *(const unsigned*)(qkv0 + (size_t)n * 384 + 2 * lane);
    float o0, o1;
    attn_loop(qkv1, 640, 128, 256, rowptr, esrc, n, lane, blo(qp), bhi(qp), o0, o1);
    *(unsigned*)(agg + (size_t)n * 128 + 2 * lane) = pk2(gelu_f(o0), gelu_f(o1));
}

// dst type1: relation 0 (src t0) + relation 2 (src t1), summed, then gelu
__global__ __launch_bounds__(256) void hgt_attn_t1(
    const unsigned short* __restrict__ qkv0,
    const unsigned short* __restrict__ qkv1,
    const int* __restrict__ rowptr0, const int* __restrict__ esrc0,
    const int* __restrict__ rowptr2, const int* __restrict__ esrc2,
    unsigned short* __restrict__ agg, int N)
{
    const int wid = threadIdx.x >> 6, lane = threadIdx.x & 63;
    const int n = blockIdx.x * 4 + wid;
    if (n >= N) return;
    const unsigned qp = *(const unsigned*)(qkv1 + (size_t)n * 640 + 2 * lane);
    const float q0 = blo(qp), q1 = bhi(qp);
    float x0, x1, y0, y1;
    attn_loop(qkv0, 384, 128, 256, rowptr0, esrc0, n, lane, q0, q1, x0, x1);
    attn_loop(qkv1, 640, 384, 512, rowptr2, esrc2, n, lane, q0, q1, y0, y1);
    *(unsigned*)(agg + (size_t)n * 128 + 2 * lane) =
        pk2(gelu_f(x0 + y0), gelu_f(x1 + y1));
}

// ---------------------------------------------------------------------------
// Weight pack: 22 blocks of 128x128 -> bf16 A-fragment order; combined
// relation weights (W @ rel * fac) computed on the fly.
// Block order: [Win0,Win1, Wq00,cwK00,cwV00, Wq01,cwK01,cwV01,cwK02,cwV02,
//   Wa00,Wa01, Wq10,cwK10,cwV10, Wq11,cwK11,cwV11,cwK12,cwV12, Wa10,Wa11]
// ---------------------------------------------------------------------------
__global__ void hgt_pack(
    const float* __restrict__ W_in, const float* __restrict__ b_in,
    const float* __restrict__ Wk, const float* __restrict__ bk,
    const float* __restrict__ Wq, const float* __restrict__ bq,
    const float* __restrict__ Wv, const float* __restrict__ bv,
    const float* __restrict__ Wa, const float* __restrict__ ba,
    const float* __restrict__ a_rel, const float* __restrict__ m_rel,
    const float* __restrict__ p_rel,
    unsigned short* __restrict__ Bp, float* __restrict__ bp)
{
    const int bid = blockIdx.x;
    const float* Wsrc = nullptr;
    const float* bsrc = nullptr;
    int l = -1, r = 0, kv = 0;
    if      (bid <  2) { Wsrc = W_in + (size_t)bid * 16384; bsrc = b_in + bid * 128; }
    else if (bid == 2) { Wsrc = Wq;                bsrc = bq; }
    else if (bid <= 4) { l = 0; r = 0; kv = bid - 3; }
    else if (bid == 5) { Wsrc = Wq + 16384;        bsrc = bq + 128; }
    else if (bid <= 7) { l = 0; r = 1; kv = bid - 6; }
    else if (bid <= 9) { l = 0; r = 2; kv = bid - 8; }
    else if (bid == 10){ Wsrc = Wa;                bsrc = ba; }
    else if (bid == 11){ Wsrc = Wa + 16384;        bsrc = ba + 128; }
    else if (bid == 12){ Wsrc = Wq + 2 * 16384;    bsrc = bq + 256; }
    else if (bid <= 14){ l = 1; r = 0; kv = bid - 13; }
    else if (bid == 15){ Wsrc = Wq + 3 * 16384;    bsrc = bq + 384; }
    else if (bid <= 17){ l = 1; r = 1; kv = bid - 16; }
    else if (bid <= 19){ l = 1; r = 2; kv = bid - 18; }
    else if (bid == 20){ Wsrc = Wa + 2 * 16384;    bsrc = ba + 256; }
    else               { Wsrc = Wa + 3 * 16384;    bsrc = ba + 384; }

    const bool iscw = (l >= 0);
    const float* rel = nullptr;
    if (iscw) {
        const int st = (r == 0) ? 0 : 1;
        Wsrc = (kv ? Wv : Wk) + (size_t)(l * 2 + st) * 16384;
        bsrc = (kv ? bv : bk) + (l * 2 + st) * 128;
        rel  = (kv ? m_rel : a_rel) + (size_t)(l * 3 + r) * 4096;
    }

    for (int i = threadIdx.x; i < 16384; i += 256) {
        const int mt = i >> 11, kt = (i >> 9) & 3, ln = (i >> 3) & 63, j = i & 7;
        const int m = mt * 16 + (ln & 15);              // outch
        const int k = kt * 32 + (ln >> 4) * 8 + j;      // inch
        float v;
        if (!iscw) {
            v = Wsrc[k * 128 + m];
        } else {
            const int h = m >> 5, e = m & 31;
            const float fac = kv ? 1.0f
                : p_rel[(l * 3 + r) * 4 + h] * 0.17677669529663687f;
            const float* wr = Wsrc + (size_t)k * 128 + h * 32;
            const float* rc = rel + h * 1024 + e;
            float s = 0.f;
#pragma unroll
            for (int d = 0; d < 32; ++d) s = fmaf(wr[d], rc[d * 32], s);
            v = s * fac;
        }
        Bp[(size_t)bid * 16384 + i] = f2b(v);
    }
    if (threadIdx.x < 128) {
        const int n = threadIdx.x;
        float v;
        if (!iscw) {
            v = bsrc[n];
        } else {
            const int h = n >> 5, e = n & 31;
            const float fac = kv ? 1.0f
                : p_rel[(l * 3 + r) * 4 + h] * 0.17677669529663687f;
            const float* rc = rel + h * 1024 + e;
            float s = 0.f;
#pragma unroll
            for (int d = 0; d < 32; ++d) s = fmaf(bsrc[h * 32 + d], rc[d * 32], s);
            v = s * fac;
        }
        bp[bid * 128 + n] = v;
    }
}

// --------------------- CSR construction (fused, 3 relations) ----------------
// deg layout: [r0: N1][r1: N0][r2: N1]; rowptr: [N1+1][N0+1][N1+1]
__global__ void hgt_hist(const int* __restrict__ d0, const int* __restrict__ d1,
                         const int* __restrict__ d2, int E, int N0v, int N1v,
                         int* __restrict__ deg)
{
    const int r = blockIdx.y;
    const int e = blockIdx.x * 256 + threadIdx.x;
    if (e >= E) return;
    const int* dd = (r == 0) ? d0 : (r == 1) ? d1 : d2;
    const int doff = (r == 0) ? 0 : (r == 1) ? N1v : (N1v + N0v);
    atomicAdd(&deg[doff + dd[e]], 1);
}

__global__ void hgt_scan1(const int* __restrict__ deg, int* __restrict__ rowptr,
                          int* __restrict__ bsums, int N0v, int N1v)
{
    const int r = blockIdx.y;
    const int Nd = (r == 1) ? N0v : N1v;
    const int n  = Nd + 1;
    if (blockIdx.x * 512 >= n) return;
    const int doff = (r == 0) ? 0 : (r == 1) ? N1v : (N1v + N0v);
    const int roff = (r == 0) ? 0 : (r == 1) ? (N1v + 1) : (N1v + N0v + 2);
    __shared__ int s[512];
    const int tid = threadIdx.x;
    const int i = blockIdx.x * 512 + tid;
    const int v = (i < Nd) ? deg[doff + i] : 0;
    s[tid] = v;
    __syncthreads();
    for (int off = 1; off < 512; off <<= 1) {
        const int t = (tid >= off) ? s[tid - off] : 0;
        __syncthreads();
        s[tid] += t;
        __syncthreads();
    }
    if (i < n) rowptr[roff + i] = s[tid] - v;       // exclusive
    if (tid == 511) bsums[r * 256 + blockIdx.x] = s[511];
}

__global__ void hgt_scan2(int* __restrict__ bsums)
{
    const int r = blockIdx.x;
    __shared__ int s[256];
    const int t = threadIdx.x;
    const int v = bsums[r * 256 + t];     // zero-initialized beyond live blocks
    s[t] = v;
    __syncthreads();
    for (int off = 1; off < 256; off <<= 1) {
        const int u = (t >= off) ? s[t - off] : 0;
        __syncthreads();
        s[t] += u;
        __syncthreads();
    }
    bsums[r * 256 + t] = s[t] - v;        // exclusive
}

__global__ void hgt_scan3(int* __restrict__ rowptr, const int* __restrict__ bsums,
                          int N0v, int N1v)
{
    const int r = blockIdx.y;
    const int n = ((r == 1) ? N0v : N1v) + 1;
    const int i = blockIdx.x * 512 + threadIdx.x;
    if (i >= n) return;
    const int roff = (r == 0) ? 0 : (r == 1) ? (N1v + 1) : (N1v + N0v + 2);
    rowptr[roff + i] += bsums[r * 256 + blockIdx.x];
}

__global__ void hgt_fill(const int* __restrict__ s0, const int* __restrict__ d0,
                         const int* __restrict__ s1, const int* __restrict__ d1,
                         const int* __restrict__ s2, const int* __restrict__ d2,
                         int E, int N0v, int N1v,
                         const int* __restrict__ rowptr, int* __restrict__ cnt,
                         int* __restrict__ esrc)
{
    const int r = blockIdx.y;
    const int e = blockIdx.x * 256 + threadIdx.x;
    if (e >= E) return;
    const int* ss = (r == 0) ? s0 : (r == 1) ? s1 : s2;
    const int* dd = (r == 0) ? d0 : (r == 1) ? d1 : d2;
    const int doff = (r == 0) ? 0 : (r == 1) ? N1v : (N1v + N0v);
    const int roff = (r == 0) ? 0 : (r == 1) ? (N1v + 1) : (N1v + N0v + 2);
    const int d = dd[e];
    const int pos = atomicAdd(&cnt[doff + d], 1);
    esrc[(size_t)r * E + rowptr[roff + d] + pos] = ss[e];
}

// ---------------------------------------------------------------------------
extern "C" void kernel_launch(void* const* d_in, const int* in_sizes, int n_in,
                              void* d_out, int out_size, void* d_ws, size_t ws_size,
                              hipStream_t stream)
{
    const float* x0  = (const float*)d_in[0];
    const float* x1  = (const float*)d_in[1];
    const int* src0 = (const int*)d_in[2];
    const int* dst0 = (const int*)d_in[3];
    const int* src1 = (const int*)d_in[4];
    const int* dst1 = (const int*)d_in[5];
    const int* src2 = (const int*)d_in[6];
    const int* dst2 = (const int*)d_in[7];
    const float* W_in = (const float*)d_in[8];
    const float* b_in = (const float*)d_in[9];
    const float* Wk = (const float*)d_in[10];
    const float* bk = (const float*)d_in[11];
    const float* Wq = (const float*)d_in[12];
    const float* bq = (const float*)d_in[13];
    const float* Wv = (const float*)d_in[14];
    const float* bv = (const float*)d_in[15];
    const float* Wa = (const float*)d_in[16];
    const float* ba = (const float*)d_in[17];
    const float* skip = (const float*)d_in[18];
    const float* a_rel = (const float*)d_in[19];
    const float* m_rel = (const float*)d_in[20];
    const float* p_rel = (const float*)d_in[21];

    const int N0 = in_sizes[0] / HID;   // 100000
    const int N1 = in_sizes[1] / HID;   // 50000
    const int E  = in_sizes[2];         // 200000
    float* out = (float*)d_out;
    (void)n_in; (void)out_size; (void)ws_size;

    // ---- workspace carve (256B aligned) ----
    char* p = (char*)d_ws;
    auto carve = [&](size_t bytes) -> char* {
        char* q = p;
        p += (bytes + 255) & ~(size_t)255;
        return q;
    };
    unsigned short* hbf  = (unsigned short*)carve((size_t)(N0 + N1) * 128 * 2);
    unsigned short* qkv0 = (unsigned short*)carve((size_t)N0 * 384 * 2);
    unsigned short* qkv1 = (unsigned short*)carve((size_t)N1 * 640 * 2);
    unsigned short* agg  = (unsigned short*)carve((size_t)(N0 + N1) * 128 * 2);
    unsigned short* packW = (unsigned short*)carve((size_t)22 * 16384 * 2);
    float* packb = (float*)carve((size_t)22 * 128 * 4);
    int* rowptr = (int*)carve((size_t)(N0 + 2 * N1 + 3) * 4);
    int* esrc   = (int*)carve((size_t)3 * E * 4);
    // zero-region: deg + cnt + bsums (one memset)
    char* zbase = carve(0);
    int* deg   = (int*)carve((size_t)(N0 + 2 * N1) * 4);
    int* cnt   = (int*)carve((size_t)(N0 + 2 * N1) * 4);
    int* bsums = (int*)carve(3 * 256 * 4);
    const size_t zbytes = (size_t)((char*)(bsums + 3 * 256) - zbase);

    unsigned short* hbf1 = hbf + (size_t)N0 * 128;
    unsigned short* agg0 = agg;
    unsigned short* agg1 = agg + (size_t)N0 * 128;
    const int* rp0 = rowptr;                      // dst t1
    const int* rp1 = rowptr + (N1 + 1);           // dst t0
    const int* rp2 = rowptr + (N1 + N0 + 2);      // dst t1
    const int* es0 = esrc;
    const int* es1 = esrc + (size_t)E;
    const int* es2 = esrc + (size_t)2 * E;

    // ---- CSR build (6 dispatches) ----
    hipMemsetAsync(zbase, 0, zbytes, stream);
    const int eb = (E + 255) / 256;
    const int nbx = (N0 + 1 + 511) / 512;
    hgt_hist <<<dim3(eb, 3), 256, 0, stream>>>(dst0, dst1, dst2, E, N0, N1, deg);
    hgt_scan1<<<dim3(nbx, 3), 512, 0, stream>>>(deg, rowptr, bsums, N0, N1);
    hgt_scan2<<<3, 256, 0, stream>>>(bsums);
    hgt_scan3<<<dim3(nbx, 3), 512, 0, stream>>>(rowptr, bsums, N0, N1);
    hgt_fill <<<dim3(eb, 3), 256, 0, stream>>>(src0, dst0, src1, dst1, src2, dst2,
                                               E, N0, N1, rowptr, cnt, (int*)esrc);

    // ---- weight pack (combined rel weights on the fly) ----
    hgt_pack<<<22, 256, 0, stream>>>(W_in, b_in, Wk, bk, Wq, bq, Wv, bv, Wa, ba,
                                     a_rel, m_rel, p_rel, packW, packb);

    auto mb = [](int M) { return (M + 127) / 128; };

    // ---- in-proj: h0 -> d_out cols [0:128) + hbf ----
    mfma_gemm<1, 1><<<dim3(1, mb(N0)), 256, 0, stream>>>(
        x0, 128, packW + 0 * 16384, packb + 0 * 128,
        hbf, 128, out, OLD, nullptr, nullptr, N0);
    mfma_gemm<1, 1><<<dim3(1, mb(N1)), 256, 0, stream>>>(
        x1, 128, packW + 1 * 16384, packb + 1 * 128,
        hbf1, 128, out + (size_t)N0 * OLD, OLD, nullptr, nullptr, N1);

    for (int l = 0; l < 2; ++l) {
        const int qkv0_blk = l ? 12 : 2;
        const int qkv1_blk = l ? 15 : 5;
        const int out0_blk = l ? 20 : 10;
        const int out1_blk = l ? 21 : 11;

        // fused q|kr|vr GEMMs
        mfma_gemm<0, 0><<<dim3(3, mb(N0)), 256, 0, stream>>>(
            hbf, 128, packW + (size_t)qkv0_blk * 16384, packb + qkv0_blk * 128,
            qkv0, 384, nullptr, 0, nullptr, nullptr, N0);
        mfma_gemm<0, 0><<<dim3(5, mb(N1)), 256, 0, stream>>>(
            hbf1, 128, packW + (size_t)qkv1_blk * 16384, packb + qkv1_blk * 128,
            qkv1, 640, nullptr, 0, nullptr, nullptr, N1);

        // attention (gelu fused)
        hgt_attn_t0<<<(N0 + 3) / 4, 256, 0, stream>>>(
            qkv0, qkv1, rp1, es1, agg0, N0);
        hgt_attn_t1<<<(N1 + 3) / 4, 256, 0, stream>>>(
            qkv0, qkv1, rp0, es0, rp2, es2, agg1, N1);

        // out-proj + skip-mix -> d_out cols [(l+1)*128) + hbf
        mfma_gemm<0, 2><<<dim3(1, mb(N0)), 256, 0, stream>>>(
            agg0, 128, packW + (size_t)out0_blk * 16384, packb + out0_blk * 128,
            hbf, 128, out + (size_t)(l + 1) * 128, OLD,
            hbf, skip + l * 2 + 0, N0);
        mfma_gemm<0, 2><<<dim3(1, mb(N1)), 256, 0, stream>>>(
            agg1, 128, packW + (size_t)out1_blk * 16384, packb + out1_blk * 128,
            hbf1, 128, out + (size_t)N0 * OLD + (size_t)(l + 1) * 128, OLD,
            hbf1, skip + l * 2 + 1, N1);
    }
}